// Round 4
// baseline (548.097 us; speedup 1.0000x reference)
//
#include <hip/hip_runtime.h>

// NNConvCritic on MI355X (gfx950).
// R4: latency attack. edge_kernel software-pipelined (prefetch next ea/x/gq
// during K-loop), msgbuf removed (direct ds_add_f32 K-partials into gacc,
// 2 barriers/iter), x pre-converted to f16. stats_kernel: no global atomics
// (per-block partials -> gstats, reduced in bn). prep parallelized. No memset.
// Pipeline: prep -> xconv -> stats -> bn -> sumx -> edge -> critic.

#define E_EDGES   800000
#define N_NODES   50000
#define G_GRAPHS  64
#define EDGE_GRID 512
#define STAT_GRID 512
#define NIT       (E_EDGES / 64)   // 12500

typedef _Float16 f16x2 __attribute__((ext_vector_type(2)));
typedef _Float16 f16x8 __attribute__((ext_vector_type(8)));
typedef __fp16   fp16x2 __attribute__((ext_vector_type(2)));
typedef float    f32x4 __attribute__((ext_vector_type(4)));
typedef unsigned u32x4 __attribute__((ext_vector_type(4)));

union H2U { f16x2 h; unsigned u; };
union F8U { f16x8 v; f16x2 h2[4]; u32x4 u4; };

__device__ __forceinline__ f16x2 pkrtz(float a, float b) {
  fp16x2 r = __builtin_amdgcn_cvt_pkrtz(a, b);
  return __builtin_bit_cast(f16x2, r);
}

// ---------------------------------------------------------------------------
// prep (70 blocks): f16 B-fragment tables. Bbuf [s(0..32)][nt(0..1)][lane][r]
// (s<32: W2' K-slices; s==32: b2 row-trick). Bw1 [nt(0..3)][lane][r].
// ---------------------------------------------------------------------------
__global__ __launch_bounds__(256) void prep_kernel(
    const float* __restrict__ W2, const float* __restrict__ b2,
    const float* __restrict__ W1, unsigned* __restrict__ Bbuf,
    unsigned* __restrict__ Bw1)
{
  int idx = blockIdx.x * 256 + threadIdx.x;
  if (idx < 33 * 512) {
    int r = idx & 3, lane = (idx >> 2) & 63, nt = (idx >> 8) & 1, s = idx >> 9;
    int q = lane >> 4, nl = lane & 15, n = nt * 16 + nl;
    float v0 = 0.f, v1 = 0.f;
    if (n < 20) {
      if (s < 32) {
        int K0 = s * 32 + q * 8 + 2 * r;
        v0 = W2[(K0 >> 4) * 320 + (K0 & 15) * 20 + n];
        v1 = W2[((K0 + 1) >> 4) * 320 + ((K0 + 1) & 15) * 20 + n];
      } else if (q < 2) {
        int i0 = q * 8 + 2 * r;
        v0 = b2[i0 * 20 + n];
        v1 = b2[(i0 + 1) * 20 + n];
      }
    }
    H2U pk; pk.h = pkrtz(v0, v1);
    Bbuf[idx] = pk.u;
  } else {
    int idx2 = idx - 33 * 512;  // [0,1024)
    int r = idx2 & 3, lane = (idx2 >> 2) & 63, nt = idx2 >> 8;
    int q = lane >> 4, nl = lane & 15, n = nt * 16 + nl;
    int k0 = q * 8 + 2 * r;
    float v0 = (k0 < 16)     ? W1[k0 * 64 + n]       : 0.f;
    float v1 = (k0 + 1 < 16) ? W1[(k0 + 1) * 64 + n] : 0.f;
    H2U pk; pk.h = pkrtz(v0, v1);
    Bw1[idx2] = pk.u;
  }
}

// ---------------------------------------------------------------------------
// xconv: x (f32) -> xh (packed f16 pairs), same pkrtz rounding as before.
// ---------------------------------------------------------------------------
__global__ __launch_bounds__(256) void xconv_kernel(
    const float* __restrict__ x, unsigned* __restrict__ xh)
{
  int i = blockIdx.x * 256 + threadIdx.x;
  if (i < N_NODES * 8) {
    H2U pk; pk.h = pkrtz(x[2 * i], x[2 * i + 1]);
    xh[i] = pk.u;
  }
}

// ---------------------------------------------------------------------------
// stats: S = EA^T EA + column sums m via MFMA(a,a); per-block LDS reduce ->
// gstats[block][272] plain stores (NO global atomics).
// ---------------------------------------------------------------------------
__global__ __launch_bounds__(256) void stats_kernel(
    const float* __restrict__ ea, float* __restrict__ gstats)
{
  __shared__ float red[4][272];
  int tid = threadIdx.x, lane = tid & 63, wave = tid >> 6;
  int nl = lane & 15, q = lane >> 4;
  int gw = blockIdx.x * 4 + wave;
  f32x4 acc = (f32x4){0.f, 0.f, 0.f, 0.f};
  float ms = 0.f;
  for (int c0 = gw; c0 < E_EDGES / 32; c0 += STAT_GRID * 4) {
    const float* p = ea + (size_t)(c0 * 32 + q * 8) * 16 + nl;
    float v0 = p[0],  v1 = p[16], v2 = p[32],  v3 = p[48];
    float v4 = p[64], v5 = p[80], v6 = p[96],  v7 = p[112];
    ms += (v0 + v1) + (v2 + v3) + (v4 + v5) + (v6 + v7);
    F8U av;
    av.h2[0] = pkrtz(v0, v1); av.h2[1] = pkrtz(v2, v3);
    av.h2[2] = pkrtz(v4, v5); av.h2[3] = pkrtz(v6, v7);
    acc = __builtin_amdgcn_mfma_f32_16x16x32_f16(av.v, av.v, acc, 0, 0, 0);
  }
  ms += __shfl_xor(ms, 16, 64);
  ms += __shfl_xor(ms, 32, 64);
#pragma unroll
  for (int r = 0; r < 4; ++r) red[wave][(q * 4 + r) * 16 + nl] = acc[r];
  if (q == 0) red[wave][256 + nl] = ms;
  __syncthreads();
  for (int v = tid; v < 272; v += 256)
    gstats[(size_t)blockIdx.x * 272 + v] =
        red[0][v] + red[1][v] + red[2][v] + red[3][v];
}

// ---------------------------------------------------------------------------
// bn: reduce gstats, then per-channel scale/shift (folds b1 into shift).
// ---------------------------------------------------------------------------
__global__ __launch_bounds__(256) void bn_kernel(
    const float* __restrict__ gstats, const float* __restrict__ W1,
    const float* __restrict__ b1, const float* __restrict__ gamma,
    const float* __restrict__ beta, float* __restrict__ sc,
    float* __restrict__ sh)
{
  __shared__ float S[272];
  int t = threadIdx.x;
  for (int v = t; v < 272; v += 256) {
    float s = 0.f;
    for (int b = 0; b < STAT_GRID; ++b) s += gstats[(size_t)b * 272 + v];
    S[v] = s;
  }
  __syncthreads();
  if (t < 64) {
    float w[16];
#pragma unroll
    for (int j = 0; j < 16; ++j) w[j] = W1[j * 64 + t];
    const float invE = 1.0f / (float)E_EDGES;
    float mw = 0.f;
#pragma unroll
    for (int j = 0; j < 16; ++j) mw += S[256 + j] * w[j];
    mw *= invE;
    float qf = 0.f;
    for (int j = 0; j < 16; ++j) {
      float tt = 0.f;
#pragma unroll
      for (int j2 = 0; j2 < 16; ++j2) tt += S[j * 16 + j2] * w[j2];
      qf += w[j] * tt;
    }
    qf *= invE;
    float b = b1[t];
    float meanH = mw + b;
    float eh2 = qf + 2.f * b * mw + b * b;
    float var = eh2 - meanH * meanH;
    float s = gamma[t] * rsqrtf(var + 1e-5f);
    sc[t] = s;
    sh[t] = beta[t] + (b - meanH) * s;
  }
}

// ---------------------------------------------------------------------------
// sumx: per-graph x column sums + node count (batch sorted -> binary search).
// ---------------------------------------------------------------------------
__global__ __launch_bounds__(256) void sumx_kernel(
    const float* __restrict__ x, const int* __restrict__ batch,
    float* __restrict__ sumx, float* __restrict__ cntf)
{
  int g = blockIdx.x, t = threadIdx.x;
  __shared__ int se[2];
  if (t < 2) {
    int key = g + t;
    int lo = 0, hi = N_NODES;
    while (lo < hi) {
      int mid = (lo + hi) >> 1;
      if (batch[mid] < key) lo = mid + 1; else hi = mid;
    }
    se[t] = lo;
  }
  __syncthreads();
  int start = se[0], end = se[1];
  int c = t & 15, rr = t >> 4;
  float s = 0.f;
  for (int n = start + rr; n < end; n += 16) s += x[(size_t)n * 16 + c];
  __shared__ float red[256];
  red[t] = s;
  __syncthreads();
#pragma unroll
  for (int st = 128; st >= 16; st >>= 1) {
    if (t < st) red[t] += red[t + st];
    __syncthreads();
  }
  if (t < 16) sumx[g * 16 + t] = red[t];
  if (t == 0) cntf[g] = (float)(end - start);
}

// ---------------------------------------------------------------------------
// edge_kernel: software-pipelined. Per 64-edge iteration:
//   h-stage (MFMA, hh write) | barrier | prefetch it+1 (ea, xh gather, gq)
//   | K-loop (72 MFMA) | ds_add_f32 partials into gacc | barrier.
// One gpart flush per block at the end. No global atomics, 2 barriers/iter.
// ---------------------------------------------------------------------------
__global__ __launch_bounds__(256, 2) void edge_kernel(
    const unsigned* __restrict__ xh, const float* __restrict__ ea,
    const int* __restrict__ ei, const int* __restrict__ batch,
    const float* __restrict__ sc, const float* __restrict__ sh,
    const unsigned* __restrict__ Bbuf, const unsigned* __restrict__ Bw1v,
    float* __restrict__ gpart)
{
  __shared__ unsigned hh[4 * 64 * 17];   // [tile][channel][m(16) pad 17]
  __shared__ float gacc[G_GRAPHS * 20];  // per-graph running sums
  __shared__ int gq[2][64];              // edge->graph, ping-pong
  const int tid = threadIdx.x;
  const int lane = tid & 63, wave = tid >> 6;
  const int nl = lane & 15, q = lane >> 4;
  const int* srcp = ei;
  const int* dstp = ei + E_EDGES;

  for (int v = tid; v < G_GRAPHS * 20; v += 256) gacc[v] = 0.f;

  // persistent B fragments
  F8U bb[8][2];
#pragma unroll
  for (int sl = 0; sl < 8; ++sl)
#pragma unroll
    for (int nt = 0; nt < 2; ++nt)
      bb[sl][nt].u4 =
          ((const u32x4*)Bbuf)[((wave * 8 + sl) * 2 + nt) * 64 + lane];
  F8U bx[2];
  if (wave == 3) {
    bx[0].u4 = ((const u32x4*)Bbuf)[(32 * 2 + 0) * 64 + lane];
    bx[1].u4 = ((const u32x4*)Bbuf)[(32 * 2 + 1) * 64 + lane];
  }
  F8U bw1[4];
#pragma unroll
  for (int nt = 0; nt < 4; ++nt)
    bw1[nt].u4 = ((const u32x4*)Bw1v)[nt * 64 + lane];
  float scv[4], shv[4];
#pragma unroll
  for (int nt = 0; nt < 4; ++nt) {
    scv[nt] = sc[nt * 16 + nl];
    shv[nt] = sh[nt * 16 + nl];
  }
  const int hbase = (16 * wave + (q >> 1)) * 17 + nl;
  const int qh = q & 1;  // which 8-float half of x this lane packs

  // ---- prologue: load iteration-0 operands ----
  int it = blockIdx.x;
  f32x4 eaA = (f32x4){0.f,0.f,0.f,0.f}, eaB = eaA;
  u32x4 xpn[4];
  {
    if (q < 2) {
      const float* p = ea + (size_t)(it * 64 + wave * 16 + nl) * 16 + q * 8;
      eaA = *(const f32x4*)p;
      eaB = *(const f32x4*)(p + 4);
    }
#pragma unroll
    for (int t = 0; t < 4; ++t) {
      int s0 = srcp[it * 64 + t * 16 + nl];
      xpn[t] = ((const u32x4*)xh)[s0 * 2 + qh];
    }
    if (wave == 0) gq[0][lane] = batch[dstp[it * 64 + lane]];
  }
  __syncthreads();  // gacc init + gq[0] visible

  int p = 0;
  for (; it < NIT; it += EDGE_GRID, p ^= 1) {
    // ---- h-stage: this wave's 16-edge tile, all 64 channels ----
    {
      F8U aEA;
      if (q < 2) {
        aEA.h2[0] = pkrtz(eaA[0], eaA[1]); aEA.h2[1] = pkrtz(eaA[2], eaA[3]);
        aEA.h2[2] = pkrtz(eaB[0], eaB[1]); aEA.h2[3] = pkrtz(eaB[2], eaB[3]);
      } else {
        aEA.u4 = (u32x4){0u, 0u, 0u, 0u};
      }
#pragma unroll
      for (int nt = 0; nt < 4; ++nt) {
        f32x4 hD = __builtin_amdgcn_mfma_f32_16x16x32_f16(
            aEA.v, bw1[nt].v, (f32x4){0.f, 0.f, 0.f, 0.f}, 0, 0, 0);
#pragma unroll
        for (int r = 0; r < 4; ++r) {
          float h = fmaxf(hD[r] * scv[nt] + shv[nt], 0.f);
          H2U pk; pk.h = pkrtz(h, h);  // packed-duplicated
          hh[(wave * 64 + nt * 16 + nl) * 17 + q * 4 + r] = pk.u;
        }
      }
    }
    // current x fragments (xpn about to be reused for prefetch)
    F8U xp[4];
#pragma unroll
    for (int t = 0; t < 4; ++t) xp[t].u4 = xpn[t];
    __syncthreads();  // barrier 1: hh complete

    // ---- prefetch iteration it+EDGE_GRID (overlaps the K-loop) ----
    int itn = it + EDGE_GRID;
    if (itn < NIT) {
      if (q < 2) {
        const float* pn =
            ea + (size_t)(itn * 64 + wave * 16 + nl) * 16 + q * 8;
        eaA = *(const f32x4*)pn;
        eaB = *(const f32x4*)(pn + 4);
      }
#pragma unroll
      for (int t = 0; t < 4; ++t) {
        int s1 = srcp[itn * 64 + t * 16 + nl];
        xpn[t] = ((const u32x4*)xh)[s1 * 2 + qh];
      }
      if (wave == 0) gq[p ^ 1][lane] = batch[dstp[itn * 64 + lane]];
    }

    // ---- K-loop: A[m][K] = h[m][K>>4] * x[m][K&15] ----
    f32x4 acc0[4], acc1[4];
#pragma unroll
    for (int t = 0; t < 4; ++t) {
      acc0[t] = (f32x4){0.f, 0.f, 0.f, 0.f};
      acc1[t] = (f32x4){0.f, 0.f, 0.f, 0.f};
    }
#pragma unroll
    for (int sl = 0; sl < 8; ++sl) {
#pragma unroll
      for (int t = 0; t < 4; ++t) {
        H2U hu; hu.u = hh[hbase + t * 1088 + sl * 34];
        F8U av;
        av.h2[0] = hu.h * xp[t].h2[0];
        av.h2[1] = hu.h * xp[t].h2[1];
        av.h2[2] = hu.h * xp[t].h2[2];
        av.h2[3] = hu.h * xp[t].h2[3];
        acc0[t] = __builtin_amdgcn_mfma_f32_16x16x32_f16(
            av.v, bb[sl][0].v, acc0[t], 0, 0, 0);
        acc1[t] = __builtin_amdgcn_mfma_f32_16x16x32_f16(
            av.v, bb[sl][1].v, acc1[t], 0, 0, 0);
      }
    }
    if (wave == 3) {  // b2 extra K-step: A = x (coefficient-1 trick)
#pragma unroll
      for (int t = 0; t < 4; ++t) {
        F8U av;
        if (q < 2) av = xp[t];
        else       av.u4 = (u32x4){0u, 0u, 0u, 0u};
        acc0[t] = __builtin_amdgcn_mfma_f32_16x16x32_f16(
            av.v, bx[0].v, acc0[t], 0, 0, 0);
        acc1[t] = __builtin_amdgcn_mfma_f32_16x16x32_f16(
            av.v, bx[1].v, acc1[t], 0, 0, 0);
      }
    }

    // ---- K-partials straight into per-graph LDS sums (ds_add_f32) ----
#pragma unroll
    for (int t = 0; t < 4; ++t) {
      int rowb = t * 16 + q * 4;
#pragma unroll
      for (int r = 0; r < 4; ++r) {
        int gi = gq[p][rowb + r] * 20;
        atomicAdd(&gacc[gi + nl], acc0[t][r]);
        if (nl < 4) atomicAdd(&gacc[gi + 16 + nl], acc1[t][r]);
      }
    }
    __syncthreads();  // barrier 2: hh reads + gq[p^1] write ordered
  }

  // ---- one flush per block: private gpart slice ----
  float* gp = gpart + (size_t)blockIdx.x * (G_GRAPHS * 20);
  for (int v = tid; v < G_GRAPHS * 20; v += 256) gp[v] = gacc[v];
}

// ---------------------------------------------------------------------------
// critic: block per graph. Reduce gpart slices; pooled = (msgsum +
// sumx@root_w + cnt*bias)/max(cnt,1); 2-layer MLP.
// ---------------------------------------------------------------------------
__global__ __launch_bounds__(256) void critic_kernel(
    const float* __restrict__ gpart, const float* __restrict__ sumx,
    const float* __restrict__ cntf, const float* __restrict__ root_w,
    const float* __restrict__ bias, const float* __restrict__ a,
    const float* __restrict__ Wc1, const float* __restrict__ bc1,
    const float* __restrict__ Wc2, const float* __restrict__ bc2,
    float* __restrict__ out)
{
  int g = blockIdx.x, t = threadIdx.x;
  __shared__ float part[240];
  __shared__ float pooled[20];
  if (t < 240) {
    int col = t % 20, r = t / 20;  // 12 row groups
    float s = 0.f;
    for (int sl = r; sl < EDGE_GRID; sl += 12)
      s += gpart[(size_t)sl * (G_GRAPHS * 20) + g * 20 + col];
    part[t] = s;
  }
  __syncthreads();
  if (t < 20) {
    float s = 0.f;
#pragma unroll
    for (int r = 0; r < 12; ++r) s += part[r * 20 + t];
    float cnt = cntf[g];
    float base = bias[t] * cnt;
#pragma unroll
    for (int i = 0; i < 16; ++i) base += sumx[g * 16 + i] * root_w[i * 20 + t];
    pooled[t] = (s + base) / fmaxf(cnt, 1.f);
  }
  __syncthreads();
  float z = bc1[t];
#pragma unroll
  for (int j = 0; j < 20; ++j) z += pooled[j] * Wc1[j * 256 + t];
#pragma unroll
  for (int j = 0; j < 8; ++j) z += a[g * 8 + j] * Wc1[(20 + j) * 256 + t];
  z = fmaxf(z, 0.f);
  float pr = z * Wc2[t];
#pragma unroll
  for (int off = 32; off >= 1; off >>= 1) pr += __shfl_down(pr, off, 64);
  __shared__ float red[4];
  if ((t & 63) == 0) red[t >> 6] = pr;
  __syncthreads();
  if (t == 0) out[g] = red[0] + red[1] + red[2] + red[3] + bc2[0];
}

// ---------------------------------------------------------------------------
extern "C" void kernel_launch(void* const* d_in, const int* in_sizes, int n_in,
                              void* d_out, int out_size, void* d_ws,
                              size_t ws_size, hipStream_t stream) {
  const float* x         = (const float*)d_in[0];
  const float* edge_attr = (const float*)d_in[1];
  const float* a         = (const float*)d_in[2];
  const int*   ei        = (const int*)d_in[3];
  const int*   batch     = (const int*)d_in[4];
  const float* W1        = (const float*)d_in[5];
  const float* b1        = (const float*)d_in[6];
  const float* gamma     = (const float*)d_in[7];
  const float* beta      = (const float*)d_in[8];
  const float* W2        = (const float*)d_in[9];
  const float* b2        = (const float*)d_in[10];
  const float* root_w    = (const float*)d_in[11];
  const float* bias      = (const float*)d_in[12];
  const float* Wc1       = (const float*)d_in[13];
  const float* bc1       = (const float*)d_in[14];
  const float* Wc2       = (const float*)d_in[15];
  const float* bc2       = (const float*)d_in[16];
  float* out = (float*)d_out;

  // ws layout (floats) — every region fully written before read, no memset
  float* wsf     = (float*)d_ws;
  float* sc      = wsf;                 // 64
  float* sh      = wsf + 64;            // 64
  float* sumx    = wsf + 128;           // 1024
  float* cntf    = wsf + 1152;          // 64
  unsigned* Bw1  = (unsigned*)(wsf + 1216);   // 1024 u32
  unsigned* Bbuf = (unsigned*)(wsf + 2240);   // 16896 u32
  float* gstats  = wsf + 19136;         // STAT_GRID*272 = 139264
  unsigned* xhp  = (unsigned*)(wsf + 158400); // N*8 = 400000 u32
  float* gpart   = wsf + 558400;        // EDGE_GRID*1280 = 655360

  prep_kernel<<<70, 256, 0, stream>>>(W2, b2, W1, Bbuf, Bw1);
  xconv_kernel<<<(N_NODES * 8 + 255) / 256, 256, 0, stream>>>(x, xhp);
  stats_kernel<<<STAT_GRID, 256, 0, stream>>>(edge_attr, gstats);
  bn_kernel<<<1, 256, 0, stream>>>(gstats, W1, b1, gamma, beta, sc, sh);
  sumx_kernel<<<G_GRAPHS, 256, 0, stream>>>(x, batch, sumx, cntf);
  edge_kernel<<<EDGE_GRID, 256, 0, stream>>>(xhp, edge_attr, ei, batch, sc,
                                             sh, Bbuf, Bw1, gpart);
  critic_kernel<<<G_GRAPHS, 256, 0, stream>>>(gpart, sumx, cntf, root_w, bias,
                                              a, Wc1, bc1, Wc2, bc2, out);
}

// Round 5
// 262.023 us; speedup vs baseline: 2.0918x; 2.0918x over previous
//
#include <hip/hip_runtime.h>

// NNConvCritic on MI355X (gfx950).
// R5: kill LDS float-atomic CAS loops (evidence: ~5.6cyc/lane-op fit across
// R3/R4). Per-graph accumulation now uses NATIVE integer ds_add_u32 into
// per-wave fixed-point slices (scale 2^17; quantization error ~1e-6 after
// pooling /cnt). bn's serial 512-way reduce (est ~100+us) replaced by a
// parallel reduce_stats kernel over transposed gstatsT.
// Pipeline: prep -> xconv -> stats -> reduce -> bn -> sumx -> edge -> critic.

#define E_EDGES   800000
#define N_NODES   50000
#define G_GRAPHS  64
#define EDGE_GRID 512
#define STAT_GRID 512
#define NIT       (E_EDGES / 64)   // 12500
#define QSCALE    131072.0f        // 2^17
#define QINV      (1.0f / 131072.0f)

typedef _Float16 f16x2 __attribute__((ext_vector_type(2)));
typedef _Float16 f16x8 __attribute__((ext_vector_type(8)));
typedef __fp16   fp16x2 __attribute__((ext_vector_type(2)));
typedef float    f32x4 __attribute__((ext_vector_type(4)));
typedef unsigned u32x4 __attribute__((ext_vector_type(4)));

union H2U { f16x2 h; unsigned u; };
union F8U { f16x8 v; f16x2 h2[4]; u32x4 u4; };

__device__ __forceinline__ f16x2 pkrtz(float a, float b) {
  fp16x2 r = __builtin_amdgcn_cvt_pkrtz(a, b);
  return __builtin_bit_cast(f16x2, r);
}

// ---------------------------------------------------------------------------
// prep (70 blocks): f16 B-fragment tables. Bbuf [s(0..32)][nt(0..1)][lane][r]
// (s<32: W2' K-slices; s==32: b2 row-trick). Bw1 [nt(0..3)][lane][r].
// ---------------------------------------------------------------------------
__global__ __launch_bounds__(256) void prep_kernel(
    const float* __restrict__ W2, const float* __restrict__ b2,
    const float* __restrict__ W1, unsigned* __restrict__ Bbuf,
    unsigned* __restrict__ Bw1)
{
  int idx = blockIdx.x * 256 + threadIdx.x;
  if (idx < 33 * 512) {
    int r = idx & 3, lane = (idx >> 2) & 63, nt = (idx >> 8) & 1, s = idx >> 9;
    int q = lane >> 4, nl = lane & 15, n = nt * 16 + nl;
    float v0 = 0.f, v1 = 0.f;
    if (n < 20) {
      if (s < 32) {
        int K0 = s * 32 + q * 8 + 2 * r;
        v0 = W2[(K0 >> 4) * 320 + (K0 & 15) * 20 + n];
        v1 = W2[((K0 + 1) >> 4) * 320 + ((K0 + 1) & 15) * 20 + n];
      } else if (q < 2) {
        int i0 = q * 8 + 2 * r;
        v0 = b2[i0 * 20 + n];
        v1 = b2[(i0 + 1) * 20 + n];
      }
    }
    H2U pk; pk.h = pkrtz(v0, v1);
    Bbuf[idx] = pk.u;
  } else {
    int idx2 = idx - 33 * 512;  // [0,1024)
    int r = idx2 & 3, lane = (idx2 >> 2) & 63, nt = idx2 >> 8;
    int q = lane >> 4, nl = lane & 15, n = nt * 16 + nl;
    int k0 = q * 8 + 2 * r;
    float v0 = (k0 < 16)     ? W1[k0 * 64 + n]       : 0.f;
    float v1 = (k0 + 1 < 16) ? W1[(k0 + 1) * 64 + n] : 0.f;
    H2U pk; pk.h = pkrtz(v0, v1);
    Bw1[idx2] = pk.u;
  }
}

// ---------------------------------------------------------------------------
// xconv: x (f32) -> xh (packed f16 pairs).
// ---------------------------------------------------------------------------
__global__ __launch_bounds__(256) void xconv_kernel(
    const float* __restrict__ x, unsigned* __restrict__ xh)
{
  int i = blockIdx.x * 256 + threadIdx.x;
  if (i < N_NODES * 8) {
    H2U pk; pk.h = pkrtz(x[2 * i], x[2 * i + 1]);
    xh[i] = pk.u;
  }
}

// ---------------------------------------------------------------------------
// stats: S = EA^T EA + column sums m via MFMA(a,a); per-block LDS reduce ->
// TRANSPOSED gstatsT[v(272)][block(512)] so the next reduce reads coalesced.
// ---------------------------------------------------------------------------
__global__ __launch_bounds__(256) void stats_kernel(
    const float* __restrict__ ea, float* __restrict__ gstatsT)
{
  __shared__ float red[4][272];
  int tid = threadIdx.x, lane = tid & 63, wave = tid >> 6;
  int nl = lane & 15, q = lane >> 4;
  int gw = blockIdx.x * 4 + wave;
  f32x4 acc = (f32x4){0.f, 0.f, 0.f, 0.f};
  float ms = 0.f;
  for (int c0 = gw; c0 < E_EDGES / 32; c0 += STAT_GRID * 4) {
    const float* p = ea + (size_t)(c0 * 32 + q * 8) * 16 + nl;
    float v0 = p[0],  v1 = p[16], v2 = p[32],  v3 = p[48];
    float v4 = p[64], v5 = p[80], v6 = p[96],  v7 = p[112];
    ms += (v0 + v1) + (v2 + v3) + (v4 + v5) + (v6 + v7);
    F8U av;
    av.h2[0] = pkrtz(v0, v1); av.h2[1] = pkrtz(v2, v3);
    av.h2[2] = pkrtz(v4, v5); av.h2[3] = pkrtz(v6, v7);
    acc = __builtin_amdgcn_mfma_f32_16x16x32_f16(av.v, av.v, acc, 0, 0, 0);
  }
  ms += __shfl_xor(ms, 16, 64);
  ms += __shfl_xor(ms, 32, 64);
#pragma unroll
  for (int r = 0; r < 4; ++r) red[wave][(q * 4 + r) * 16 + nl] = acc[r];
  if (q == 0) red[wave][256 + nl] = ms;
  __syncthreads();
  for (int v = tid; v < 272; v += 256)
    gstatsT[(size_t)v * STAT_GRID + blockIdx.x] =
        red[0][v] + red[1][v] + red[2][v] + red[3][v];
}

// ---------------------------------------------------------------------------
// reduce_stats: 272 blocks; block v sums gstatsT[v][0..511] (coalesced).
// ---------------------------------------------------------------------------
__global__ __launch_bounds__(256) void reduce_stats_kernel(
    const float* __restrict__ gstatsT, float* __restrict__ Sred)
{
  int v = blockIdx.x, t = threadIdx.x;
  float s = gstatsT[(size_t)v * STAT_GRID + t] +
            gstatsT[(size_t)v * STAT_GRID + t + 256];
#pragma unroll
  for (int off = 32; off >= 1; off >>= 1) s += __shfl_down(s, off, 64);
  __shared__ float red[4];
  if ((t & 63) == 0) red[t >> 6] = s;
  __syncthreads();
  if (t == 0) Sred[v] = red[0] + red[1] + red[2] + red[3];
}

// ---------------------------------------------------------------------------
// bn_final: per-channel scale/shift from reduced moments (folds b1 in).
// ---------------------------------------------------------------------------
__global__ void bn_kernel(const float* __restrict__ Sred,
                          const float* __restrict__ W1,
                          const float* __restrict__ b1,
                          const float* __restrict__ gamma,
                          const float* __restrict__ beta,
                          float* __restrict__ sc, float* __restrict__ sh)
{
  int c = threadIdx.x;  // 64 threads
  float w[16];
#pragma unroll
  for (int j = 0; j < 16; ++j) w[j] = W1[j * 64 + c];
  const float invE = 1.0f / (float)E_EDGES;
  float mw = 0.f;
#pragma unroll
  for (int j = 0; j < 16; ++j) mw += Sred[256 + j] * w[j];
  mw *= invE;
  float qf = 0.f;
  for (int j = 0; j < 16; ++j) {
    float tt = 0.f;
#pragma unroll
    for (int j2 = 0; j2 < 16; ++j2) tt += Sred[j * 16 + j2] * w[j2];
    qf += w[j] * tt;
  }
  qf *= invE;
  float b = b1[c];
  float meanH = mw + b;
  float eh2 = qf + 2.f * b * mw + b * b;
  float var = eh2 - meanH * meanH;
  float s = gamma[c] * rsqrtf(var + 1e-5f);
  sc[c] = s;
  sh[c] = beta[c] + (b - meanH) * s;
}

// ---------------------------------------------------------------------------
// sumx: per-graph x column sums + node count (batch sorted -> binary search).
// ---------------------------------------------------------------------------
__global__ __launch_bounds__(256) void sumx_kernel(
    const float* __restrict__ x, const int* __restrict__ batch,
    float* __restrict__ sumx, float* __restrict__ cntf)
{
  int g = blockIdx.x, t = threadIdx.x;
  __shared__ int se[2];
  if (t < 2) {
    int key = g + t;
    int lo = 0, hi = N_NODES;
    while (lo < hi) {
      int mid = (lo + hi) >> 1;
      if (batch[mid] < key) lo = mid + 1; else hi = mid;
    }
    se[t] = lo;
  }
  __syncthreads();
  int start = se[0], end = se[1];
  int c = t & 15, rr = t >> 4;
  float s = 0.f;
  for (int n = start + rr; n < end; n += 16) s += x[(size_t)n * 16 + c];
  __shared__ float red[256];
  red[t] = s;
  __syncthreads();
#pragma unroll
  for (int st = 128; st >= 16; st >>= 1) {
    if (t < st) red[t] += red[t + st];
    __syncthreads();
  }
  if (t < 16) sumx[g * 16 + t] = red[t];
  if (t == 0) cntf[g] = (float)(end - start);
}

// ---------------------------------------------------------------------------
// edge_kernel: software-pipelined; per-graph accumulation via NATIVE int LDS
// atomics (ds_add_u32) into per-wave fixed-point slices. 2 barriers/iter.
// ---------------------------------------------------------------------------
__global__ __launch_bounds__(256, 2) void edge_kernel(
    const unsigned* __restrict__ xh, const float* __restrict__ ea,
    const int* __restrict__ ei, const int* __restrict__ batch,
    const float* __restrict__ sc, const float* __restrict__ sh,
    const unsigned* __restrict__ Bbuf, const unsigned* __restrict__ Bw1v,
    float* __restrict__ gpart)
{
  __shared__ unsigned hh[4 * 64 * 17];    // [tile][channel][m(16) pad 17]
  __shared__ int gaccI[4][G_GRAPHS * 20]; // per-WAVE fixed-point sums
  __shared__ int gq[2][64];               // edge->graph, ping-pong
  const int tid = threadIdx.x;
  const int lane = tid & 63, wave = tid >> 6;
  const int nl = lane & 15, q = lane >> 4;
  const int* srcp = ei;
  const int* dstp = ei + E_EDGES;

  for (int v = tid; v < 4 * G_GRAPHS * 20; v += 256)
    gaccI[v >> 10][v & 1023] = 0;  // 1280 not pow2; do explicit 2D
  // (re-zero properly below; the above covers v<4096 of 5120)
  for (int v = 4096 + tid; v < 4 * G_GRAPHS * 20; v += 256)
    gaccI[v / 1280][v % 1280] = 0;
  // NOTE: first loop's indexing [v>>10][v&1023] is wrong for slices of 1280;
  // replaced by a clean full pass:
  __syncthreads();
  for (int v = tid; v < 4 * G_GRAPHS * 20; v += 256)
    ((int*)gaccI)[v] = 0;

  // persistent B fragments
  F8U bb[8][2];
#pragma unroll
  for (int sl = 0; sl < 8; ++sl)
#pragma unroll
    for (int nt = 0; nt < 2; ++nt)
      bb[sl][nt].u4 =
          ((const u32x4*)Bbuf)[((wave * 8 + sl) * 2 + nt) * 64 + lane];
  F8U bx[2];
  if (wave == 3) {
    bx[0].u4 = ((const u32x4*)Bbuf)[(32 * 2 + 0) * 64 + lane];
    bx[1].u4 = ((const u32x4*)Bbuf)[(32 * 2 + 1) * 64 + lane];
  }
  F8U bw1[4];
#pragma unroll
  for (int nt = 0; nt < 4; ++nt)
    bw1[nt].u4 = ((const u32x4*)Bw1v)[nt * 64 + lane];
  float scv[4], shv[4];
#pragma unroll
  for (int nt = 0; nt < 4; ++nt) {
    scv[nt] = sc[nt * 16 + nl];
    shv[nt] = sh[nt * 16 + nl];
  }
  const int hbase = (16 * wave + (q >> 1)) * 17 + nl;
  const int qh = q & 1;

  // ---- prologue: load iteration-0 operands ----
  int it = blockIdx.x;
  f32x4 eaA = (f32x4){0.f,0.f,0.f,0.f}, eaB = eaA;
  u32x4 xpn[4];
  {
    if (q < 2) {
      const float* p = ea + (size_t)(it * 64 + wave * 16 + nl) * 16 + q * 8;
      eaA = *(const f32x4*)p;
      eaB = *(const f32x4*)(p + 4);
    }
#pragma unroll
    for (int t = 0; t < 4; ++t) {
      int s0 = srcp[it * 64 + t * 16 + nl];
      xpn[t] = ((const u32x4*)xh)[s0 * 2 + qh];
    }
    if (wave == 0) gq[0][lane] = batch[dstp[it * 64 + lane]];
  }
  __syncthreads();  // gacc init + gq[0] visible

  int p = 0;
  for (; it < NIT; it += EDGE_GRID, p ^= 1) {
    // ---- h-stage ----
    {
      F8U aEA;
      if (q < 2) {
        aEA.h2[0] = pkrtz(eaA[0], eaA[1]); aEA.h2[1] = pkrtz(eaA[2], eaA[3]);
        aEA.h2[2] = pkrtz(eaB[0], eaB[1]); aEA.h2[3] = pkrtz(eaB[2], eaB[3]);
      } else {
        aEA.u4 = (u32x4){0u, 0u, 0u, 0u};
      }
#pragma unroll
      for (int nt = 0; nt < 4; ++nt) {
        f32x4 hD = __builtin_amdgcn_mfma_f32_16x16x32_f16(
            aEA.v, bw1[nt].v, (f32x4){0.f, 0.f, 0.f, 0.f}, 0, 0, 0);
#pragma unroll
        for (int r = 0; r < 4; ++r) {
          float h = fmaxf(hD[r] * scv[nt] + shv[nt], 0.f);
          H2U pk; pk.h = pkrtz(h, h);  // packed-duplicated
          hh[(wave * 64 + nt * 16 + nl) * 17 + q * 4 + r] = pk.u;
        }
      }
    }
    F8U xp[4];
#pragma unroll
    for (int t = 0; t < 4; ++t) xp[t].u4 = xpn[t];
    __syncthreads();  // barrier 1: hh complete

    // ---- prefetch it+EDGE_GRID (overlaps K-loop + atomics) ----
    int itn = it + EDGE_GRID;
    if (itn < NIT) {
      if (q < 2) {
        const float* pn =
            ea + (size_t)(itn * 64 + wave * 16 + nl) * 16 + q * 8;
        eaA = *(const f32x4*)pn;
        eaB = *(const f32x4*)(pn + 4);
      }
#pragma unroll
      for (int t = 0; t < 4; ++t) {
        int s1 = srcp[itn * 64 + t * 16 + nl];
        xpn[t] = ((const u32x4*)xh)[s1 * 2 + qh];
      }
      if (wave == 0) gq[p ^ 1][lane] = batch[dstp[itn * 64 + lane]];
    }

    // ---- K-loop ----
    f32x4 acc0[4], acc1[4];
#pragma unroll
    for (int t = 0; t < 4; ++t) {
      acc0[t] = (f32x4){0.f, 0.f, 0.f, 0.f};
      acc1[t] = (f32x4){0.f, 0.f, 0.f, 0.f};
    }
#pragma unroll
    for (int sl = 0; sl < 8; ++sl) {
#pragma unroll
      for (int t = 0; t < 4; ++t) {
        H2U hu; hu.u = hh[hbase + t * 1088 + sl * 34];
        F8U av;
        av.h2[0] = hu.h * xp[t].h2[0];
        av.h2[1] = hu.h * xp[t].h2[1];
        av.h2[2] = hu.h * xp[t].h2[2];
        av.h2[3] = hu.h * xp[t].h2[3];
        acc0[t] = __builtin_amdgcn_mfma_f32_16x16x32_f16(
            av.v, bb[sl][0].v, acc0[t], 0, 0, 0);
        acc1[t] = __builtin_amdgcn_mfma_f32_16x16x32_f16(
            av.v, bb[sl][1].v, acc1[t], 0, 0, 0);
      }
    }
    if (wave == 3) {  // b2 extra K-step
#pragma unroll
      for (int t = 0; t < 4; ++t) {
        F8U av;
        if (q < 2) av = xp[t];
        else       av.u4 = (u32x4){0u, 0u, 0u, 0u};
        acc0[t] = __builtin_amdgcn_mfma_f32_16x16x32_f16(
            av.v, bx[0].v, acc0[t], 0, 0, 0);
        acc1[t] = __builtin_amdgcn_mfma_f32_16x16x32_f16(
            av.v, bx[1].v, acc1[t], 0, 0, 0);
      }
    }

    // ---- fixed-point K-partials into THIS WAVE's slice (ds_add_u32) ----
    int* my = gaccI[wave];
#pragma unroll
    for (int t = 0; t < 4; ++t) {
      int rowb = t * 16 + q * 4;
#pragma unroll
      for (int r = 0; r < 4; ++r) {
        int gi = gq[p][rowb + r] * 20;
        atomicAdd(&my[gi + nl], __float2int_rn(acc0[t][r] * QSCALE));
        if (nl < 4)
          atomicAdd(&my[gi + 16 + nl], __float2int_rn(acc1[t][r] * QSCALE));
      }
    }
    __syncthreads();  // barrier 2
  }

  // ---- one flush per block: sum 4 int slices -> float gpart slice ----
  float* gp = gpart + (size_t)blockIdx.x * (G_GRAPHS * 20);
  for (int v = tid; v < G_GRAPHS * 20; v += 256)
    gp[v] = (float)(gaccI[0][v] + gaccI[1][v] + gaccI[2][v] + gaccI[3][v]) *
            QINV;
}

// ---------------------------------------------------------------------------
// critic: block per graph. Reduce gpart slices; pooled = (msgsum +
// sumx@root_w + cnt*bias)/max(cnt,1); 2-layer MLP.
// ---------------------------------------------------------------------------
__global__ __launch_bounds__(256) void critic_kernel(
    const float* __restrict__ gpart, const float* __restrict__ sumx,
    const float* __restrict__ cntf, const float* __restrict__ root_w,
    const float* __restrict__ bias, const float* __restrict__ a,
    const float* __restrict__ Wc1, const float* __restrict__ bc1,
    const float* __restrict__ Wc2, const float* __restrict__ bc2,
    float* __restrict__ out)
{
  int g = blockIdx.x, t = threadIdx.x;
  __shared__ float part[240];
  __shared__ float pooled[20];
  if (t < 240) {
    int col = t % 20, r = t / 20;  // 12 row groups
    float s = 0.f;
    for (int sl = r; sl < EDGE_GRID; sl += 12)
      s += gpart[(size_t)sl * (G_GRAPHS * 20) + g * 20 + col];
    part[t] = s;
  }
  __syncthreads();
  if (t < 20) {
    float s = 0.f;
#pragma unroll
    for (int r = 0; r < 12; ++r) s += part[r * 20 + t];
    float cnt = cntf[g];
    float base = bias[t] * cnt;
#pragma unroll
    for (int i = 0; i < 16; ++i) base += sumx[g * 16 + i] * root_w[i * 20 + t];
    pooled[t] = (s + base) / fmaxf(cnt, 1.f);
  }
  __syncthreads();
  float z = bc1[t];
#pragma unroll
  for (int j = 0; j < 20; ++j) z += pooled[j] * Wc1[j * 256 + t];
#pragma unroll
  for (int j = 0; j < 8; ++j) z += a[g * 8 + j] * Wc1[(20 + j) * 256 + t];
  z = fmaxf(z, 0.f);
  float pr = z * Wc2[t];
#pragma unroll
  for (int off = 32; off >= 1; off >>= 1) pr += __shfl_down(pr, off, 64);
  __shared__ float red[4];
  if ((t & 63) == 0) red[t >> 6] = pr;
  __syncthreads();
  if (t == 0) out[g] = red[0] + red[1] + red[2] + red[3] + bc2[0];
}

// ---------------------------------------------------------------------------
extern "C" void kernel_launch(void* const* d_in, const int* in_sizes, int n_in,
                              void* d_out, int out_size, void* d_ws,
                              size_t ws_size, hipStream_t stream) {
  const float* x         = (const float*)d_in[0];
  const float* edge_attr = (const float*)d_in[1];
  const float* a         = (const float*)d_in[2];
  const int*   ei        = (const int*)d_in[3];
  const int*   batch     = (const int*)d_in[4];
  const float* W1        = (const float*)d_in[5];
  const float* b1        = (const float*)d_in[6];
  const float* gamma     = (const float*)d_in[7];
  const float* beta      = (const float*)d_in[8];
  const float* W2        = (const float*)d_in[9];
  const float* b2        = (const float*)d_in[10];
  const float* root_w    = (const float*)d_in[11];
  const float* bias      = (const float*)d_in[12];
  const float* Wc1       = (const float*)d_in[13];
  const float* bc1       = (const float*)d_in[14];
  const float* Wc2       = (const float*)d_in[15];
  const float* bc2       = (const float*)d_in[16];
  float* out = (float*)d_out;

  // ws layout (floats) — every region fully written before read, no memset
  float* wsf     = (float*)d_ws;
  float* sc      = wsf;                 // 64
  float* sh      = wsf + 64;            // 64
  float* sumx    = wsf + 128;           // 1024
  float* cntf    = wsf + 1152;          // 64
  float* Sred    = wsf + 1216;          // 272
  unsigned* Bw1  = (unsigned*)(wsf + 1488);   // 1024 u32
  unsigned* Bbuf = (unsigned*)(wsf + 2512);   // 16896 u32
  float* gstatsT = wsf + 19408;         // 272*512 = 139264
  unsigned* xhp  = (unsigned*)(wsf + 158672); // N*8 = 400000 u32
  float* gpart   = wsf + 558672;        // EDGE_GRID*1280 = 655360

  prep_kernel<<<70, 256, 0, stream>>>(W2, b2, W1, Bbuf, Bw1);
  xconv_kernel<<<(N_NODES * 8 + 255) / 256, 256, 0, stream>>>(x, xhp);
  stats_kernel<<<STAT_GRID, 256, 0, stream>>>(edge_attr, gstatsT);
  reduce_stats_kernel<<<272, 256, 0, stream>>>(gstatsT, Sred);
  bn_kernel<<<1, 64, 0, stream>>>(Sred, W1, b1, gamma, beta, sc, sh);
  sumx_kernel<<<G_GRAPHS, 256, 0, stream>>>(x, batch, sumx, cntf);
  edge_kernel<<<EDGE_GRID, 256, 0, stream>>>(xhp, edge_attr, ei, batch, sc,
                                             sh, Bbuf, Bw1, gpart);
  critic_kernel<<<G_GRAPHS, 256, 0, stream>>>(gpart, sumx, cntf, root_w, bias,
                                              a, Wc1, bc1, Wc2, bc2, out);
}